// Round 16
// baseline (3023.258 us; speedup 1.0000x reference)
//
#include <hip/hip_runtime.h>
#include <hip/hip_fp16.h>
#include <stdint.h>

typedef unsigned short ushort_t;
typedef unsigned int uint_t;
typedef unsigned long long ull_t;
typedef _Float16 half8 __attribute__((ext_vector_type(8)));
typedef float f32x4 __attribute__((ext_vector_type(4)));

#define TSTEPS 512
#define BATCH  64
#define ISZ    512
#define HSZ    1024
#define GSZ    4096
#define NB     256
#define NTH    1024
#define DHFRAG 65536  // halves per dh fragment buffer (128 KB)

static constexpr size_t OFF_XPREV = (size_t)TSTEPS * BATCH * HSZ;
static constexpr size_t OFF_H     = OFF_XPREV + (size_t)BATCH * 1024;
static constexpr size_t OFF_HP    = OFF_H  + (size_t)BATCH * HSZ;
static constexpr size_t OFF_C     = OFF_HP + (size_t)BATCH * HSZ;
static constexpr size_t OFF_M     = OFF_C  + (size_t)BATCH * HSZ;
static constexpr size_t OFF_REG   = OFF_M  + (size_t)BATCH * GSZ;

#define TH_RAW 0.1f
#define TH_QNT 0.1015625f

__device__ __forceinline__ float qA(float x) {
  float v = rintf(x * 256.0f);
  v = fminf(fmaxf(v, -32768.0f), 32767.0f);
  return v * 0.00390625f;
}
__device__ __forceinline__ float qN(float x) {
  float v = rintf(x * 256.0f);
  v = fminf(fmaxf(v, -512.0f), 511.0f);
  return v * 0.00390625f;
}
__device__ __forceinline__ float sigm(float x) { return 1.0f / (1.0f + expf(-x)); }

// ---------------------------------------------------------------------------
__global__ __launch_bounds__(256) void xscan_kernel(const float* __restrict__ x,
                                                    __half* __restrict__ dx16,
                                                    float* __restrict__ out_xprev) {
  const int gid = blockIdx.x * blockDim.x + threadIdx.x;
  float xp = 0.0f;
  #pragma unroll 8
  for (int t = 0; t < TSTEPS; t++) {
    float xq = qA(x[(size_t)t * (BATCH * ISZ) + gid]);
    float d  = xq - xp;
    float da = fabsf(d);
    dx16[(size_t)t * (BATCH * ISZ) + gid] = __float2half((da < TH_QNT) ? 0.0f : d);
    if (da >= TH_RAW) xp = xq;
  }
  const int b = gid >> 9;
  const int i = gid & 511;
  out_xprev[(size_t)b * 1024 + i]       = xp;
  out_xprev[(size_t)b * 1024 + 512 + i] = 0.0f;
}

// ---------------------------------------------------------------------------
// Epilogue-only classic grid barrier (validated r7..r15).
// ---------------------------------------------------------------------------
__device__ __forceinline__ void gbar_arrive(int* flags, int e) {
  asm volatile("s_waitcnt vmcnt(0)" ::: "memory");
  __syncthreads();
  if (threadIdx.x == 0) {
    __hip_atomic_store(&flags[blockIdx.x], e, __ATOMIC_RELAXED, __HIP_MEMORY_SCOPE_AGENT);
  }
}
__device__ __forceinline__ void gbar_wait(int* flags, int e) {
  if (threadIdx.x < 64) {
    const ull_t* f64 = (const ull_t*)flags;
    const int l = threadIdx.x;
    bool done;
    do {
      ull_t a = __hip_atomic_load(f64 + l,      __ATOMIC_RELAXED, __HIP_MEMORY_SCOPE_AGENT);
      ull_t c = __hip_atomic_load(f64 + 64 + l, __ATOMIC_RELAXED, __HIP_MEMORY_SCOPE_AGENT);
      bool ok = ((int)a >= e) & ((int)(a >> 32) >= e) &
                ((int)c >= e) & ((int)(c >> 32) >= e);
      done = __all(ok);
      if (!done) __builtin_amdgcn_s_sleep(2);
    } while (!done);
  }
  __syncthreads();
}

// ---------------------------------------------------------------------------
// Round-16 scan = r13 data path (validated 2.66ms, bit-exact) with the grid
// barrier replaced by PER-PRODUCER-BLOCK FLAGS + WAVE-GRANULAR WAITS:
//  - producer block jb publishes flags[jb]=t+1 after its dh cells drain;
//  - consumer wave (kg) polls only its 64 producers (jb in [kg*64,kg*64+64)),
//    one u64 flag load per lane (lanes 0..31 cover the range).
// Blocks self-synchronize pairwise -> skew pipelines instead of a 256-block
// convoy. 2-buffer safety: P writes cell(P,t+1) only after consuming all
// flags>=t => every C finished step t-1's reads (incl. cell(P,t-1)).
// x-pass kept on the post-wait path as h-frag L3-latency cover (r15 lesson).
// part[..][17] padding + XCD-chunked jb map retained.
// ---------------------------------------------------------------------------
__global__ __launch_bounds__(NTH, 4) void scan_kernel(
    const __half* __restrict__ dx16, const float* __restrict__ w_ih,
    const float* __restrict__ w_hh, const float* __restrict__ b_ih,
    const float* __restrict__ b_hh, float* __restrict__ out,
    __half* __restrict__ dh16, float* __restrict__ partials,
    int* flags, int* flagsE) {
  __shared__ __align__(16) unsigned char dxbuf[2][65536];
  __shared__ float part[4][64][17];
  __shared__ float red[256];

  const int tid  = threadIdx.x;
  const int wid  = tid >> 6;
  const int lane = tid & 63;
  const int bt   = wid >> 2;          // b-tile 0..3
  const int kg   = wid & 3;           // k-group 0..3
  const int lr   = lane & 15;
  const int lq   = lane >> 4;
  const int lkb  = lq * 16;
  const int jb   = (blockIdx.x & 7) * 32 + (blockIdx.x >> 3);  // XCD-chunked

  // ---- one-time: W fragments (fp16) into registers (identical to r13) ----
  const int wrow = jb * 4 + (lr & 3) + (lr >> 2) * HSZ;
  half8 wx[4], wh[8];
  #pragma unroll
  for (int kt = 0; kt < 4; ++kt) {
    const float* p = w_ih + (size_t)wrow * ISZ + kg * 128 + kt * 32 + lq * 8;
    half8 v;
    #pragma unroll
    for (int e = 0; e < 8; ++e) v[e] = (_Float16)p[e];
    wx[kt] = v;
  }
  #pragma unroll
  for (int kt = 0; kt < 8; ++kt) {
    const float* p = w_hh + (size_t)wrow * HSZ + kg * 256 + kt * 32 + lq * 8;
    half8 v;
    #pragma unroll
    for (int e = 0; e < 8; ++e) v[e] = (_Float16)p[e];
    wh[kt] = v;
  }

  // combiner state (tid<256)
  const int jj = tid & 3;
  const int cb = tid >> 2;
  const int j  = jb * 4 + jj;
  const int g0 = j, g1 = j + HSZ, g2 = j + 2 * HSZ, g3 = j + 3 * HSZ;
  float m0 = 0.f, m1 = 0.f, m2 = 0.f, m3 = 0.f;
  float c = 0.0f, hp = 0.0f, h = 0.0f, regacc = 0.0f;
  if (tid < 256) {
    m0 = b_ih[g0] + b_hh[g0];
    m1 = b_ih[g1] + b_hh[g1];
    m2 = b_ih[g2] + b_hh[g2];
    m3 = b_ih[g3] + b_hh[g3];
  }
  const size_t dhcell2 = ((size_t)(jb >> 1) * 64 + cb) * 2 + (jb & 1);

  const int arow = bt * 16 + lr;
  const int akey = (arow & 7) << 4;
  const int kc0  = kg * 32 + lq;
  const int fidx = kg * 32 + (lane & 31);   // producer-flag u64 index for this wave

  // ---- prologue: stage dx[0] ----------------------------------------------
  {
    const ull_t* __restrict__ sx = (const ull_t*)dx16;
    #pragma unroll
    for (int i = 0; i < 8; ++i) {
      ull_t v = sx[i * 1024 + tid];
      const int u = i * 1024 + tid;
      const int row = u >> 7, cc = u & 127;
      *(ull_t*)(&dxbuf[0][0] + row * 1024 + ((cc * 8) ^ ((row & 7) << 4))) = v;
    }
  }
  __syncthreads();

  for (int t = 0; t < TSTEPS; t++) {
    // ---- 1. wave-granular wait on this wave's 64 producers ---------------
    {
      const ull_t* f64 = (const ull_t*)flags;
      bool done;
      do {
        ull_t v = __hip_atomic_load(f64 + fidx, __ATOMIC_RELAXED, __HIP_MEMORY_SCOPE_AGENT);
        done = __all(((int)v >= t) & ((int)(v >> 32) >= t));
        if (!done) __builtin_amdgcn_s_sleep(1);
      } while (!done);
      asm volatile("" ::: "memory");   // keep data loads below the poll
    }

    // ---- 2. issue h-frag loads (8 cells = 16 u64) -------------------------
    const ull_t* __restrict__ hb = (const ull_t*)(dh16 + (size_t)(t & 1) * DHFRAG);
    ull_t lo[8], hi[8];
    #pragma unroll
    for (int kt = 0; kt < 8; ++kt) {
      const size_t ci = ((size_t)(kc0 + kt * 4) * 64 + arow) * 2;
      lo[kt] = __hip_atomic_load(hb + ci,     __ATOMIC_RELAXED, __HIP_MEMORY_SCOPE_AGENT);
      hi[kt] = __hip_atomic_load(hb + ci + 1, __ATOMIC_RELAXED, __HIP_MEMORY_SCOPE_AGENT);
    }

    // ---- 3. x-pass (covers h-frag L3 latency) -----------------------------
    f32x4 acc = {0.f, 0.f, 0.f, 0.f};
    {
      const unsigned char* xbase = &dxbuf[t & 1][0] + arow * 1024;
      #pragma unroll
      for (int kt = 0; kt < 4; ++kt) {
        const int col = kg * 256 + kt * 64 + lkb;
        union { uint4 u; half8 hv; } U;
        U.u = *(const uint4*)(xbase + (col ^ akey));
        acc = __builtin_amdgcn_mfma_f32_16x16x32_f16(U.hv, wx[kt], acc, 0, 0, 0);
      }
    }
    // ---- 4. h-pass --------------------------------------------------------
    #pragma unroll
    for (int kt = 0; kt < 8; ++kt) {
      union { ull_t u[2]; half8 hv; } U;
      U.u[0] = lo[kt]; U.u[1] = hi[kt];
      acc = __builtin_amdgcn_mfma_f32_16x16x32_f16(U.hv, wh[kt], acc, 0, 0, 0);
    }

    // ---- 5. partials ------------------------------------------------------
    #pragma unroll
    for (int r = 0; r < 4; ++r)
      part[kg][bt * 16 + lq * 4 + r][lr] = acc[r];
    __syncthreads();

    // ---- 6. combine + gates + dh store ------------------------------------
    if (tid < 256) {
      float s0 = 0.f, s1 = 0.f, s2 = 0.f, s3 = 0.f;
      #pragma unroll
      for (int k2 = 0; k2 < 4; ++k2) {
        s0 += part[k2][cb][jj];
        s1 += part[k2][cb][4 + jj];
        s2 += part[k2][cb][8 + jj];
        s3 += part[k2][cb][12 + jj];
      }
      m0 += s0; m1 += s1; m2 += s2; m3 += s3;

      float pi = qA(m0), pf = qA(m1), pg = qA(m2), po = qA(m3);
      float gi = qN(sigm(pi));
      float gf = qN(sigm(pf));
      float gg = qN(tanhf(pg));
      float go = qN(sigm(po));
      float cn = c * gf + gi * gg;
      c = qA(cn);
      float ct = qN(tanhf(c));
      h = qA(go * ct);

      if (t < TSTEPS - 1) {
        float d  = h - hp;
        float da = fabsf(d);
        float dm = (da < TH_QNT) ? 0.0f : d;
        if (da >= TH_RAW) hp = h;
        regacc += fabsf(dm);
        ushort_t my = __half_as_ushort(__float2half(dm));   // fp16 exact for dh
        int v1 = __shfl((int)my, lane + 1, 64);
        int v2 = __shfl((int)my, lane + 2, 64);
        int v3 = __shfl((int)my, lane + 3, 64);
        if (jj == 0) {
          ull_t dw = (ull_t)my | ((ull_t)(ushort_t)v1 << 16) |
                     ((ull_t)(ushort_t)v2 << 32) | ((ull_t)(ushort_t)v3 << 48);
          ull_t* dhw = (ull_t*)(dh16 + (size_t)((t + 1) & 1) * DHFRAG);
          __hip_atomic_store(dhw + dhcell2, dw,
                             __ATOMIC_RELAXED, __HIP_MEMORY_SCOPE_AGENT);
        }
      }
    }

    // ---- 7. drain dh -> publish producer flag -----------------------------
    asm volatile("s_waitcnt vmcnt(0)" ::: "memory");
    __syncthreads();
    if (tid == 0)
      __hip_atomic_store(&flags[jb], t + 1, __ATOMIC_RELAXED, __HIP_MEMORY_SCOPE_AGENT);

    // ---- 8. shadow: out-store + next dx stage ----------------------------
    if (tid < 256)
      out[(size_t)t * (BATCH * HSZ) + (size_t)cb * HSZ + j] = h;
    if (t + 1 < TSTEPS) {
      const ull_t* __restrict__ sx =
          (const ull_t*)(dx16 + (size_t)(t + 1) * (BATCH * ISZ));
      unsigned char* dst = &dxbuf[(t + 1) & 1][0];
      #pragma unroll
      for (int i = 0; i < 8; ++i) {
        ull_t v = sx[i * 1024 + tid];
        const int u = i * 1024 + tid;
        const int row = u >> 7, cc = u & 127;
        *(ull_t*)(dst + row * 1024 + ((cc * 8) ^ ((row & 7) << 4))) = v;
      }
    }
    __syncthreads();   // dxbuf visibility + part-write separation
  }

  if (tid < 256) {  // final state dump
    out[OFF_H  + (size_t)cb * HSZ + j] = h;
    out[OFF_HP + (size_t)cb * HSZ + j] = hp;
    out[OFF_C  + (size_t)cb * HSZ + j] = c;
    out[OFF_M  + (size_t)cb * GSZ + g0] = m0;
    out[OFF_M  + (size_t)cb * GSZ + g1] = m1;
    out[OFF_M  + (size_t)cb * GSZ + g2] = m2;
    out[OFF_M  + (size_t)cb * GSZ + g3] = m3;
  }

  // deterministic reg reduction (epilogue grid barrier on flagsE)
  if (tid < 256) red[tid] = regacc;
  __syncthreads();
  for (int s = 128; s > 0; s >>= 1) {
    if (tid < s) red[tid] += red[tid + s];
    __syncthreads();
  }
  if (tid == 0)
    __hip_atomic_store(&partials[blockIdx.x], red[0], __ATOMIC_RELAXED, __HIP_MEMORY_SCOPE_AGENT);
  gbar_arrive(flagsE, 1);
  gbar_wait(flagsE, 1);
  if (blockIdx.x == 0) {
    if (tid < 256)
      red[tid] = __hip_atomic_load(&partials[tid], __ATOMIC_RELAXED, __HIP_MEMORY_SCOPE_AGENT);
    __syncthreads();
    for (int s = 128; s > 0; s >>= 1) {
      if (tid < s) red[tid] += red[tid + s];
      __syncthreads();
    }
    if (tid == 0) out[OFF_REG] = red[0];
  }
}

// ---------------------------------------------------------------------------
extern "C" void kernel_launch(void* const* d_in, const int* in_sizes, int n_in,
                              void* d_out, int out_size, void* d_ws, size_t ws_size,
                              hipStream_t stream) {
  const float* x    = (const float*)d_in[0];
  const float* w_ih = (const float*)d_in[1];
  const float* w_hh = (const float*)d_in[2];
  const float* b_ih = (const float*)d_in[3];
  const float* b_hh = (const float*)d_in[4];
  float* out = (float*)d_out;

  const size_t dx_elems = (size_t)TSTEPS * BATCH * ISZ;   // fp16: 33.5 MB
  __half* dx16     = (__half*)d_ws;
  __half* dh16     = dx16 + dx_elems;                     // 2 x DHFRAG halves
  float*  partials = (float*)(dh16 + 2 * (size_t)DHFRAG);
  int*    flags    = (int*)(partials + NB);               // producer flags (by jb)
  int*    flagsE   = flags + NB;                          // epilogue barrier
  size_t needed = (size_t)((char*)(flagsE + NB) - (char*)d_ws);
  if (ws_size < needed) return;

  (void)hipMemsetAsync(dh16, 0, 2 * (size_t)DHFRAG * sizeof(__half), stream);
  (void)hipMemsetAsync(flags, 0, 2 * NB * sizeof(int), stream);
  xscan_kernel<<<128, 256, 0, stream>>>(x, dx16, out + OFF_XPREV);
  scan_kernel<<<NB, NTH, 0, stream>>>(dx16, w_ih, w_hh, b_ih, b_hh, out,
                                      dh16, partials, flags, flagsE);
}

// Round 17
// 2581.781 us; speedup vs baseline: 1.1710x; 1.1710x over previous
//
#include <hip/hip_runtime.h>
#include <hip/hip_fp16.h>
#include <stdint.h>

typedef unsigned short ushort_t;
typedef unsigned int uint_t;
typedef unsigned long long ull_t;
typedef _Float16 half8 __attribute__((ext_vector_type(8)));
typedef float f32x4 __attribute__((ext_vector_type(4)));

#define TSTEPS 512
#define BATCH  64
#define ISZ    512
#define HSZ    1024
#define GSZ    4096
#define NB     256
#define NTH    1024
#define DHFRAG 65536  // halves per dh fragment buffer (128 KB)

static constexpr size_t OFF_XPREV = (size_t)TSTEPS * BATCH * HSZ;
static constexpr size_t OFF_H     = OFF_XPREV + (size_t)BATCH * 1024;
static constexpr size_t OFF_HP    = OFF_H  + (size_t)BATCH * HSZ;
static constexpr size_t OFF_C     = OFF_HP + (size_t)BATCH * HSZ;
static constexpr size_t OFF_M     = OFF_C  + (size_t)BATCH * HSZ;
static constexpr size_t OFF_REG   = OFF_M  + (size_t)BATCH * GSZ;

#define TH_RAW 0.1f
#define TH_QNT 0.1015625f

__device__ __forceinline__ float qA(float x) {
  float v = rintf(x * 256.0f);
  v = fminf(fmaxf(v, -32768.0f), 32767.0f);
  return v * 0.00390625f;
}
__device__ __forceinline__ float qN(float x) {
  float v = rintf(x * 256.0f);
  v = fminf(fmaxf(v, -512.0f), 511.0f);
  return v * 0.00390625f;
}
__device__ __forceinline__ float sigm(float x) { return 1.0f / (1.0f + expf(-x)); }

// ---------------------------------------------------------------------------
__global__ __launch_bounds__(256) void xscan_kernel(const float* __restrict__ x,
                                                    __half* __restrict__ dx16,
                                                    float* __restrict__ out_xprev) {
  const int gid = blockIdx.x * blockDim.x + threadIdx.x;
  float xp = 0.0f;
  #pragma unroll 8
  for (int t = 0; t < TSTEPS; t++) {
    float xq = qA(x[(size_t)t * (BATCH * ISZ) + gid]);
    float d  = xq - xp;
    float da = fabsf(d);
    dx16[(size_t)t * (BATCH * ISZ) + gid] = __float2half((da < TH_QNT) ? 0.0f : d);
    if (da >= TH_RAW) xp = xq;
  }
  const int b = gid >> 9;
  const int i = gid & 511;
  out_xprev[(size_t)b * 1024 + i]       = xp;
  out_xprev[(size_t)b * 1024 + 512 + i] = 0.0f;
}

// ---------------------------------------------------------------------------
// Split grid barrier (validated r7..r16): arrive = vmcnt drain -> sync ->
// relaxed flag store; wait = wave-0 poll -> sync. Work placed between arrive
// and wait runs in the barrier-wait shadow.
// ---------------------------------------------------------------------------
__device__ __forceinline__ void gbar_arrive(int* flags, int e) {
  asm volatile("s_waitcnt vmcnt(0)" ::: "memory");
  __syncthreads();
  if (threadIdx.x == 0) {
    __hip_atomic_store(&flags[blockIdx.x], e, __ATOMIC_RELAXED, __HIP_MEMORY_SCOPE_AGENT);
  }
}
__device__ __forceinline__ void gbar_wait(int* flags, int e) {
  if (threadIdx.x < 64) {
    const ull_t* f64 = (const ull_t*)flags;
    const int l = threadIdx.x;
    bool done;
    do {
      ull_t a = __hip_atomic_load(f64 + l,      __ATOMIC_RELAXED, __HIP_MEMORY_SCOPE_AGENT);
      ull_t c = __hip_atomic_load(f64 + 64 + l, __ATOMIC_RELAXED, __HIP_MEMORY_SCOPE_AGENT);
      bool ok = ((int)a >= e) & ((int)(a >> 32) >= e) &
                ((int)c >= e) & ((int)(c >> 32) >= e);
      done = __all(ok);
      if (!done) __builtin_amdgcn_s_sleep(2);
    } while (!done);
  }
  __syncthreads();
}

// ---------------------------------------------------------------------------
// Round-17 scan = r13 EXACT structure (best: 2.66ms, bit-exact absmax) plus
// the two orthogonal validated micro-fixes:
//  - part[4][64][17]: +1 pad kills the 4-way LDS bank conflict (r15/r16:
//    1.0e8 -> 6.7e7 measured);
//  - XCD-chunked jb map (r14): the 4 blocks sharing each out/dh 64B line sit
//    on one XCD -> L2 write-merging (WRITE 403 -> 272 MB measured).
// Everything else byte-level r13: batch-A h-frag issue -> x-pass (latency
// cover) -> batch-B issue -> consume A -> consume B; out-store in combine;
// dx staged in the arrive/wait shadow; classic grid flag barrier.
// ---------------------------------------------------------------------------
__global__ __launch_bounds__(NTH, 4) void scan_kernel(
    const __half* __restrict__ dx16, const float* __restrict__ w_ih,
    const float* __restrict__ w_hh, const float* __restrict__ b_ih,
    const float* __restrict__ b_hh, float* __restrict__ out,
    __half* __restrict__ dh16, float* __restrict__ partials, int* flags) {
  __shared__ __align__(16) unsigned char dxbuf[2][65536];  // dx double buffer
  __shared__ float part[4][64][17];
  __shared__ float red[256];

  const int tid  = threadIdx.x;
  const int wid  = tid >> 6;
  const int lane = tid & 63;
  const int bt   = wid >> 2;          // b-tile 0..3
  const int kg   = wid & 3;           // k-group 0..3
  const int lr   = lane & 15;
  const int lq   = lane >> 4;
  const int lkb  = lq * 16;
  const int jb   = (blockIdx.x & 7) * 32 + (blockIdx.x >> 3);  // XCD-chunked

  // ---- one-time: W fragments (fp16) into registers (identical to r13) ----
  const int wrow = jb * 4 + (lr & 3) + (lr >> 2) * HSZ;
  half8 wx[4], wh[8];
  #pragma unroll
  for (int kt = 0; kt < 4; ++kt) {
    const float* p = w_ih + (size_t)wrow * ISZ + kg * 128 + kt * 32 + lq * 8;
    half8 v;
    #pragma unroll
    for (int e = 0; e < 8; ++e) v[e] = (_Float16)p[e];
    wx[kt] = v;
  }
  #pragma unroll
  for (int kt = 0; kt < 8; ++kt) {
    const float* p = w_hh + (size_t)wrow * HSZ + kg * 256 + kt * 32 + lq * 8;
    half8 v;
    #pragma unroll
    for (int e = 0; e < 8; ++e) v[e] = (_Float16)p[e];
    wh[kt] = v;
  }

  // combiner state (tid<256)
  const int jj = tid & 3;
  const int cb = tid >> 2;
  const int j  = jb * 4 + jj;
  const int g0 = j, g1 = j + HSZ, g2 = j + 2 * HSZ, g3 = j + 3 * HSZ;
  float m0 = 0.f, m1 = 0.f, m2 = 0.f, m3 = 0.f;
  float c = 0.0f, hp = 0.0f, h = 0.0f, regacc = 0.0f;
  if (tid < 256) {
    m0 = b_ih[g0] + b_hh[g0];
    m1 = b_ih[g1] + b_hh[g1];
    m2 = b_ih[g2] + b_hh[g2];
    m3 = b_ih[g3] + b_hh[g3];
  }
  const size_t dhcell2 = ((size_t)(jb >> 1) * 64 + cb) * 2 + (jb & 1);

  const int arow = bt * 16 + lr;
  const int akey = (arow & 7) << 4;
  const int kc0  = kg * 32 + lq;   // h-frag cell base

  // ---- stage dx[0] --------------------------------------------------------
  {
    const ull_t* __restrict__ sx = (const ull_t*)dx16;
    #pragma unroll
    for (int i = 0; i < 8; ++i) {
      ull_t v = sx[i * 1024 + tid];
      const int u = i * 1024 + tid;
      const int row = u >> 7, cc = u & 127;
      *(ull_t*)(&dxbuf[0][0] + row * 1024 + ((cc * 8) ^ ((row & 7) << 4))) = v;
    }
  }
  __syncthreads();

  for (int t = 0; t < TSTEPS; t++) {
    const ull_t* __restrict__ hb = (const ull_t*)(dh16 + (size_t)(t & 1) * DHFRAG);
    const unsigned char* xbase = &dxbuf[t & 1][0] + arow * 1024;

    // ---- batch A of h-fragments (kt 0..3): issue loads early --------------
    ull_t lo[4], hi[4];
    #pragma unroll
    for (int kt = 0; kt < 4; ++kt) {
      const size_t ci = ((size_t)(kc0 + kt * 4) * 64 + arow) * 2;
      lo[kt] = __hip_atomic_load(hb + ci,     __ATOMIC_RELAXED, __HIP_MEMORY_SCOPE_AGENT);
      hi[kt] = __hip_atomic_load(hb + ci + 1, __ATOMIC_RELAXED, __HIP_MEMORY_SCOPE_AGENT);
    }

    f32x4 acc = {0.f, 0.f, 0.f, 0.f};
    { // ---- x-pass: 4 MFMA from LDS (overlaps batch-A load latency) --------
      #pragma unroll
      for (int kt = 0; kt < 4; ++kt) {
        const int col = kg * 256 + kt * 64 + lkb;
        union { uint4 u; half8 hv; } U;
        U.u = *(const uint4*)(xbase + (col ^ akey));
        acc = __builtin_amdgcn_mfma_f32_16x16x32_f16(U.hv, wx[kt], acc, 0, 0, 0);
      }
    }

    // ---- batch B of h-fragments (kt 4..7): issue, then consume A ---------
    ull_t lo2[4], hi2[4];
    #pragma unroll
    for (int kt = 0; kt < 4; ++kt) {
      const size_t ci = ((size_t)(kc0 + (kt + 4) * 4) * 64 + arow) * 2;
      lo2[kt] = __hip_atomic_load(hb + ci,     __ATOMIC_RELAXED, __HIP_MEMORY_SCOPE_AGENT);
      hi2[kt] = __hip_atomic_load(hb + ci + 1, __ATOMIC_RELAXED, __HIP_MEMORY_SCOPE_AGENT);
    }
    #pragma unroll
    for (int kt = 0; kt < 4; ++kt) {
      union { ull_t u[2]; half8 hv; } U;
      U.u[0] = lo[kt]; U.u[1] = hi[kt];
      acc = __builtin_amdgcn_mfma_f32_16x16x32_f16(U.hv, wh[kt], acc, 0, 0, 0);
    }
    #pragma unroll
    for (int kt = 0; kt < 4; ++kt) {
      union { ull_t u[2]; half8 hv; } U;
      U.u[0] = lo2[kt]; U.u[1] = hi2[kt];
      acc = __builtin_amdgcn_mfma_f32_16x16x32_f16(U.hv, wh[kt + 4], acc, 0, 0, 0);
    }

    // ---- partials (D layout: col=lane&15, row=(lane>>4)*4+r) -------------
    #pragma unroll
    for (int r = 0; r < 4; ++r)
      part[kg][bt * 16 + lq * 4 + r][lr] = acc[r];
    __syncthreads();

    if (tid < 256) {  // ---- combine (fixed order, identical r13) ----------
      float s0 = 0.f, s1 = 0.f, s2 = 0.f, s3 = 0.f;
      #pragma unroll
      for (int k2 = 0; k2 < 4; ++k2) {
        s0 += part[k2][cb][jj];
        s1 += part[k2][cb][4 + jj];
        s2 += part[k2][cb][8 + jj];
        s3 += part[k2][cb][12 + jj];
      }
      m0 += s0; m1 += s1; m2 += s2; m3 += s3;

      float pi = qA(m0), pf = qA(m1), pg = qA(m2), po = qA(m3);
      float gi = qN(sigm(pi));
      float gf = qN(sigm(pf));
      float gg = qN(tanhf(pg));
      float go = qN(sigm(po));
      float cn = c * gf + gi * gg;
      c = qA(cn);
      float ct = qN(tanhf(c));
      h = qA(go * ct);
      out[(size_t)t * (BATCH * HSZ) + (size_t)cb * HSZ + j] = h;

      if (t < TSTEPS - 1) {
        float d  = h - hp;
        float da = fabsf(d);
        float dm = (da < TH_QNT) ? 0.0f : d;
        if (da >= TH_RAW) hp = h;
        regacc += fabsf(dm);
        // pack 4 halves (jj=0..3 of this cb) into one u64, store to frag cell
        ushort_t my = __half_as_ushort(__float2half(dm));   // fp16 exact for dh
        int v1 = __shfl((int)my, lane + 1, 64);
        int v2 = __shfl((int)my, lane + 2, 64);
        int v3 = __shfl((int)my, lane + 3, 64);
        if (jj == 0) {
          ull_t dw = (ull_t)my | ((ull_t)(ushort_t)v1 << 16) |
                     ((ull_t)(ushort_t)v2 << 32) | ((ull_t)(ushort_t)v3 << 48);
          ull_t* dhw = (ull_t*)(dh16 + (size_t)((t + 1) & 1) * DHFRAG);
          __hip_atomic_store(dhw + dhcell2, dw,
                             __ATOMIC_RELAXED, __HIP_MEMORY_SCOPE_AGENT);
        }
      }
    }

    gbar_arrive(flags, t + 1);

    if (t + 1 < TSTEPS) {  // ---- stage dx[t+1] in the barrier-wait shadow --
      const ull_t* __restrict__ sx =
          (const ull_t*)(dx16 + (size_t)(t + 1) * (BATCH * ISZ));
      unsigned char* dst = &dxbuf[(t + 1) & 1][0];
      #pragma unroll
      for (int i = 0; i < 8; ++i) {
        ull_t v = sx[i * 1024 + tid];
        const int u = i * 1024 + tid;
        const int row = u >> 7, cc = u & 127;
        *(ull_t*)(dst + row * 1024 + ((cc * 8) ^ ((row & 7) << 4))) = v;
      }
    }

    gbar_wait(flags, t + 1);
  }

  if (tid < 256) {  // final state dump
    out[OFF_H  + (size_t)cb * HSZ + j] = h;
    out[OFF_HP + (size_t)cb * HSZ + j] = hp;
    out[OFF_C  + (size_t)cb * HSZ + j] = c;
    out[OFF_M  + (size_t)cb * GSZ + g0] = m0;
    out[OFF_M  + (size_t)cb * GSZ + g1] = m1;
    out[OFF_M  + (size_t)cb * GSZ + g2] = m2;
    out[OFF_M  + (size_t)cb * GSZ + g3] = m3;
  }

  // deterministic reg reduction
  if (tid < 256) red[tid] = regacc;
  __syncthreads();
  for (int s = 128; s > 0; s >>= 1) {
    if (tid < s) red[tid] += red[tid + s];
    __syncthreads();
  }
  if (tid == 0)
    __hip_atomic_store(&partials[blockIdx.x], red[0], __ATOMIC_RELAXED, __HIP_MEMORY_SCOPE_AGENT);
  gbar_arrive(flags, TSTEPS + 1);
  gbar_wait(flags, TSTEPS + 1);
  if (blockIdx.x == 0) {
    if (tid < 256)
      red[tid] = __hip_atomic_load(&partials[tid], __ATOMIC_RELAXED, __HIP_MEMORY_SCOPE_AGENT);
    __syncthreads();
    for (int s = 128; s > 0; s >>= 1) {
      if (tid < s) red[tid] += red[tid + s];
      __syncthreads();
    }
    if (tid == 0) out[OFF_REG] = red[0];
  }
}

// ---------------------------------------------------------------------------
extern "C" void kernel_launch(void* const* d_in, const int* in_sizes, int n_in,
                              void* d_out, int out_size, void* d_ws, size_t ws_size,
                              hipStream_t stream) {
  const float* x    = (const float*)d_in[0];
  const float* w_ih = (const float*)d_in[1];
  const float* w_hh = (const float*)d_in[2];
  const float* b_ih = (const float*)d_in[3];
  const float* b_hh = (const float*)d_in[4];
  float* out = (float*)d_out;

  const size_t dx_elems = (size_t)TSTEPS * BATCH * ISZ;   // fp16: 33.5 MB
  __half* dx16     = (__half*)d_ws;
  __half* dh16     = dx16 + dx_elems;                     // 2 x DHFRAG halves
  float*  partials = (float*)(dh16 + 2 * (size_t)DHFRAG);
  int*    flags    = (int*)(partials + NB);
  size_t needed = (size_t)((char*)(flags + NB) - (char*)d_ws);
  if (ws_size < needed) return;

  (void)hipMemsetAsync(dh16, 0, 2 * (size_t)DHFRAG * sizeof(__half), stream);
  (void)hipMemsetAsync(flags, 0, NB * sizeof(int), stream);
  xscan_kernel<<<128, 256, 0, stream>>>(x, dx16, out + OFF_XPREV);
  scan_kernel<<<NB, NTH, 0, stream>>>(dx16, w_ih, w_hh, b_ih, b_hh, out,
                                      dh16, partials, flags);
}